// Round 10
// baseline (17.053 us; speedup 1.0000x reference)
//
#include <hip/hip_runtime.h>
#include <math.h>

#define N_ROWS 8192
#define DIM    128
#define NCLASS 100
#define NBLK_A (2 * NCLASS)          // 200: class = blk%100, half-range = blk/100
#define CD     (NBLK_A * DIM)        // C partials: 200 x 128

// ws float layout: C[200*128] | invb[N_ROWS]
#define INV_OFF CD

// ---------------------------------------------------------------------------
// KA: 200 blocks x 1024 threads. Block handles class c over a 4096-row half.
// Each of 16 waves scans 256 labels (one int4/lane, ballot+rank list), then
// processes matched rows in one batch of 8 (half-wave float4, interleaved
// chains). Writes its private C row non-atomically; stores inv-norms.
__global__ void __launch_bounds__(1024)
ka_class_sums(const float* __restrict__ z, const int* __restrict__ labels,
              float* __restrict__ C, float* __restrict__ invb,
              float* __restrict__ out)
{
    __shared__ int    lists[16][64];
    __shared__ float4 Cb[16][2][32];

    const int blk  = blockIdx.x;                 // 0..199
    const int c    = (blk < NCLASS) ? blk : blk - NCLASS;
    const int roff = (blk < NCLASS) ? 0 : 4096;  // row half-range
    const int lane = threadIdx.x & 63;
    const int sub  = lane & 31;
    const int half = lane >> 5;
    const int wid  = threadIdx.x >> 6;           // 0..15
    const int base = roff + wid * 256;           // this wave's label window

    if (blk == 0 && threadIdx.x == 0) out[0] = 0.0f;

    // ---- scan 256 labels: one int4 per lane; ballot + rank -> list ----
    int cnt = 0;
    {
        int4 l4 = ((const int4*)(labels + base))[lane];
        #pragma unroll
        for (int k = 0; k < 4; ++k) {
            int lbl = (k == 0) ? l4.x : (k == 1) ? l4.y : (k == 2) ? l4.z : l4.w;
            bool hit = (lbl == c);
            unsigned long long m = __ballot(hit);
            if (hit) {
                int idx = cnt + __popcll(m & ((1ull << lane) - 1ull));
                if (idx < 64) lists[wid][idx] = base + 4 * lane + k;
            }
            cnt += __popcll(m);
        }
        if (cnt > 64) cnt = 64;
    }

    // ---- process rows 8 at a time: half h owns rows i+2k+h, k=0..3 ----
    float4 acc = make_float4(0.0f, 0.0f, 0.0f, 0.0f);
    for (int i = 0; i < cnt; i += 8) {
        int i0 = i + half, i1 = i + 2 + half, i2 = i + 4 + half, i3 = i + 6 + half;
        float w0 = (i0 < cnt) ? 1.0f : 0.0f;
        float w1 = (i1 < cnt) ? 1.0f : 0.0f;
        float w2 = (i2 < cnt) ? 1.0f : 0.0f;
        float w3 = (i3 < cnt) ? 1.0f : 0.0f;
        int r0 = lists[wid][(i0 < cnt) ? i0 : 0];
        int r1 = lists[wid][(i1 < cnt) ? i1 : 0];
        int r2 = lists[wid][(i2 < cnt) ? i2 : 0];
        int r3 = lists[wid][(i3 < cnt) ? i3 : 0];
        float4 v0 = *(const float4*)(z + (size_t)r0 * DIM + sub * 4);
        float4 v1 = *(const float4*)(z + (size_t)r1 * DIM + sub * 4);
        float4 v2 = *(const float4*)(z + (size_t)r2 * DIM + sub * 4);
        float4 v3 = *(const float4*)(z + (size_t)r3 * DIM + sub * 4);
        float s0 = v0.x * v0.x + v0.y * v0.y + v0.z * v0.z + v0.w * v0.w;
        float s1 = v1.x * v1.x + v1.y * v1.y + v1.z * v1.z + v1.w * v1.w;
        float s2 = v2.x * v2.x + v2.y * v2.y + v2.z * v2.z + v2.w * v2.w;
        float s3 = v3.x * v3.x + v3.y * v3.y + v3.z * v3.z + v3.w * v3.w;
        #pragma unroll
        for (int off = 1; off < 32; off <<= 1) {
            s0 += __shfl_xor(s0, off);
            s1 += __shfl_xor(s1, off);
            s2 += __shfl_xor(s2, off);
            s3 += __shfl_xor(s3, off);
        }
        float iv0 = rsqrtf(s0), iv1 = rsqrtf(s1);
        float iv2 = rsqrtf(s2), iv3 = rsqrtf(s3);
        if (sub == 0) {
            if (w0 != 0.0f) invb[r0] = iv0;
            if (w1 != 0.0f) invb[r1] = iv1;
            if (w2 != 0.0f) invb[r2] = iv2;
            if (w3 != 0.0f) invb[r3] = iv3;
        }
        float f0 = w0 * iv0, f1 = w1 * iv1, f2 = w2 * iv2, f3 = w3 * iv3;
        acc.x += v0.x * f0 + v1.x * f1 + v2.x * f2 + v3.x * f3;
        acc.y += v0.y * f0 + v1.y * f1 + v2.y * f2 + v3.y * f3;
        acc.z += v0.z * f0 + v1.z * f1 + v2.z * f2 + v3.z * f3;
        acc.w += v0.w * f0 + v1.w * f1 + v2.w * f2 + v3.w * f3;
    }

    Cb[wid][half][sub] = acc;
    __syncthreads();

    // ---- reduce 32 half-wave partials per dim; write private C row ----
    if (threadIdx.x < DIM) {
        int g = threadIdx.x >> 2, comp = threadIdx.x & 3;
        const float* Cf = (const float*)Cb;       // [32][32][4] flat
        float s = 0.0f;
        #pragma unroll
        for (int w = 0; w < 32; ++w) s += Cf[(w * 32 + g) * 4 + comp];
        C[(size_t)blk * DIM + threadIdx.x] = s;
    }
}

// ---------------------------------------------------------------------------
// KB: 256 blocks x 512 threads. Prefetch z/labels/inv/C-halves into registers
// BEFORE the S-scan (S = sum of all 200 partial rows), then per-row loss.
__global__ void __launch_bounds__(512)
kb_loss(const float* __restrict__ z, const int* __restrict__ labels,
        const float* __restrict__ C, const float* __restrict__ invb,
        float* __restrict__ out)
{
    const int tid  = threadIdx.x;
    const int lane = tid & 63;
    const int sub  = lane & 31;
    const int half = lane >> 5;
    const int wid  = tid >> 6;                          // 0..7
    const int hw   = (blockIdx.x * 8 + wid) * 2 + half; // 0..4095

    const int rowA = hw, rowB = hw + 4096;

    // ---- issue-early: all per-row data before the S-scan ----
    float4 vA = *(const float4*)(z + (size_t)rowA * DIM + sub * 4);
    float4 vB = *(const float4*)(z + (size_t)rowB * DIM + sub * 4);
    int   lA = labels[rowA], lB = labels[rowB];
    float iA = invb[rowA],   iB = invb[rowB];
    float4 cA0 = *(const float4*)(C + (size_t)lA * DIM + sub * 4);
    float4 cA1 = *(const float4*)(C + (size_t)(lA + NCLASS) * DIM + sub * 4);
    float4 cB0 = *(const float4*)(C + (size_t)lB * DIM + sub * 4);
    float4 cB1 = *(const float4*)(C + (size_t)(lB + NCLASS) * DIM + sub * 4);

    // ---- S-scan over 200 partial rows: 16 chunks x 32 dim-groups ----
    __shared__ float4 Sp[16][32];
    __shared__ float4 S4s[32];
    {
        int g = tid & 31, chunk = tid >> 5;
        float4 s = make_float4(0.0f, 0.0f, 0.0f, 0.0f);
        for (int cc = chunk; cc < NBLK_A; cc += 16) {
            float4 v = *(const float4*)(C + (size_t)cc * DIM + g * 4);
            s.x += v.x; s.y += v.y; s.z += v.z; s.w += v.w;
        }
        Sp[chunk][g] = s;
    }
    __syncthreads();
    if (tid < 32) {
        float4 s = make_float4(0.0f, 0.0f, 0.0f, 0.0f);
        #pragma unroll
        for (int ch = 0; ch < 16; ++ch) {
            float4 v = Sp[ch][tid];
            s.x += v.x; s.y += v.y; s.z += v.z; s.w += v.w;
        }
        S4s[tid] = s;
    }
    __syncthreads();

    float4 s4 = S4s[sub];
    float4 cA = make_float4(cA0.x + cA1.x, cA0.y + cA1.y,
                            cA0.z + cA1.z, cA0.w + cA1.w);
    float4 cB = make_float4(cB0.x + cB1.x, cB0.y + cB1.y,
                            cB0.z + cB1.z, cB0.w + cB1.w);

    float dcA = vA.x * cA.x + vA.y * cA.y + vA.z * cA.z + vA.w * cA.w;
    float dtA = vA.x * s4.x + vA.y * s4.y + vA.z * s4.z + vA.w * s4.w;
    float dcB = vB.x * cB.x + vB.y * cB.y + vB.z * cB.z + vB.w * cB.w;
    float dtB = vB.x * s4.x + vB.y * s4.y + vB.z * s4.z + vB.w * s4.w;
    #pragma unroll
    for (int off = 1; off < 32; off <<= 1) {
        dcA += __shfl_xor(dcA, off);
        dtA += __shfl_xor(dtA, off);
        dcB += __shfl_xor(dcB, off);
        dtB += __shfl_xor(dtB, off);
    }
    float lacc = -__logf((dcA * iA - 1.0f) / (dtA * iA))
                 -__logf((dcB * iB - 1.0f) / (dtB * iB));

    lacc += __shfl_xor(lacc, 32);
    __shared__ float wacc[8];
    if (lane == 0) wacc[wid] = lacc;
    __syncthreads();
    if (tid == 0) {
        float b = wacc[0] + wacc[1] + wacc[2] + wacc[3]
                + wacc[4] + wacc[5] + wacc[6] + wacc[7];
        unsafeAtomicAdd(out, b * (1.0f / (float)N_ROWS));
    }
}

extern "C" void kernel_launch(void* const* d_in, const int* in_sizes, int n_in,
                              void* d_out, int out_size, void* d_ws, size_t ws_size,
                              hipStream_t stream) {
    const float* z      = (const float*)d_in[0];
    const int*   labels = (const int*)d_in[1];
    float* out  = (float*)d_out;
    float* ws   = (float*)d_ws;
    float* C    = ws;
    float* invb = ws + INV_OFF;

    (void)in_sizes; (void)n_in; (void)out_size; (void)ws_size;

    ka_class_sums<<<NBLK_A, 1024, 0, stream>>>(z, labels, C, invb, out);
    kb_loss      <<<256,    512,  0, stream>>>(z, labels, C, invb, out);
}

// Round 11
// 16.972 us; speedup vs baseline: 1.0048x; 1.0048x over previous
//
#include <hip/hip_runtime.h>
#include <math.h>

#define N_ROWS 8192
#define DIM    128
#define NCLASS 100
#define CD     (NCLASS * DIM)       // C: 12800 floats

// ws float layout: C[CD] | invb[N_ROWS]
#define INV_OFF CD

// ---------------------------------------------------------------------------
// KA: one block per class c. 16 waves scan 512 labels each (ballot+rank list),
// then process matched rows in ONE batch of 8 (half-wave float4, 4 rows per
// half, interleaved shuffle chains). Stores inv-norms. Non-atomic C write.
__global__ void __launch_bounds__(1024)
ka_class_sums(const float* __restrict__ z, const int* __restrict__ labels,
              float* __restrict__ C, float* __restrict__ invb,
              float* __restrict__ out)
{
    __shared__ int    lists[16][64];
    __shared__ float4 Cb[16][2][32];

    const int c    = blockIdx.x;
    const int lane = threadIdx.x & 63;
    const int sub  = lane & 31;
    const int half = lane >> 5;
    const int wid  = threadIdx.x >> 6;      // 0..15
    const int base = wid * 512;

    if (c == 0 && threadIdx.x == 0) out[0] = 0.0f;

    // ---- scan 512 labels: 2 x int4 per lane; ballot + rank -> list ----
    int cnt = 0;
    #pragma unroll
    for (int it = 0; it < 2; ++it) {
        int b4 = base + it * 256;
        int4 l4 = ((const int4*)(labels + b4))[lane];
        #pragma unroll
        for (int k = 0; k < 4; ++k) {
            int lbl = (k == 0) ? l4.x : (k == 1) ? l4.y : (k == 2) ? l4.z : l4.w;
            bool hit = (lbl == c);
            unsigned long long m = __ballot(hit);
            if (hit) {
                int rank = __popcll(m & ((1ull << lane) - 1ull));
                lists[wid][cnt + rank] = b4 + 4 * lane + k;
            }
            cnt += __popcll(m);
        }
    }

    // ---- process rows 8 at a time: half h owns rows i+2k+h, k=0..3 ----
    float4 acc = make_float4(0.0f, 0.0f, 0.0f, 0.0f);
    for (int i = 0; i < cnt; i += 8) {
        int i0 = i + half, i1 = i + 2 + half, i2 = i + 4 + half, i3 = i + 6 + half;
        float w0 = (i0 < cnt) ? 1.0f : 0.0f;
        float w1 = (i1 < cnt) ? 1.0f : 0.0f;
        float w2 = (i2 < cnt) ? 1.0f : 0.0f;
        float w3 = (i3 < cnt) ? 1.0f : 0.0f;
        int r0 = lists[wid][(i0 < cnt) ? i0 : 0];
        int r1 = lists[wid][(i1 < cnt) ? i1 : 0];
        int r2 = lists[wid][(i2 < cnt) ? i2 : 0];
        int r3 = lists[wid][(i3 < cnt) ? i3 : 0];
        float4 v0 = *(const float4*)(z + (size_t)r0 * DIM + sub * 4);
        float4 v1 = *(const float4*)(z + (size_t)r1 * DIM + sub * 4);
        float4 v2 = *(const float4*)(z + (size_t)r2 * DIM + sub * 4);
        float4 v3 = *(const float4*)(z + (size_t)r3 * DIM + sub * 4);
        float s0 = v0.x * v0.x + v0.y * v0.y + v0.z * v0.z + v0.w * v0.w;
        float s1 = v1.x * v1.x + v1.y * v1.y + v1.z * v1.z + v1.w * v1.w;
        float s2 = v2.x * v2.x + v2.y * v2.y + v2.z * v2.z + v2.w * v2.w;
        float s3 = v3.x * v3.x + v3.y * v3.y + v3.z * v3.z + v3.w * v3.w;
        #pragma unroll
        for (int off = 1; off < 32; off <<= 1) {
            s0 += __shfl_xor(s0, off);
            s1 += __shfl_xor(s1, off);
            s2 += __shfl_xor(s2, off);
            s3 += __shfl_xor(s3, off);
        }
        float iv0 = rsqrtf(s0), iv1 = rsqrtf(s1);
        float iv2 = rsqrtf(s2), iv3 = rsqrtf(s3);
        if (sub == 0) {
            if (w0 != 0.0f) invb[r0] = iv0;
            if (w1 != 0.0f) invb[r1] = iv1;
            if (w2 != 0.0f) invb[r2] = iv2;
            if (w3 != 0.0f) invb[r3] = iv3;
        }
        float f0 = w0 * iv0, f1 = w1 * iv1, f2 = w2 * iv2, f3 = w3 * iv3;
        acc.x += v0.x * f0 + v1.x * f1 + v2.x * f2 + v3.x * f3;
        acc.y += v0.y * f0 + v1.y * f1 + v2.y * f2 + v3.y * f3;
        acc.z += v0.z * f0 + v1.z * f1 + v2.z * f2 + v3.z * f3;
        acc.w += v0.w * f0 + v1.w * f1 + v2.w * f2 + v3.w * f3;
    }

    Cb[wid][half][sub] = acc;
    __syncthreads();

    // ---- reduce 32 half-wave partials per dim; write C[c] ----
    if (threadIdx.x < DIM) {
        int g = threadIdx.x >> 2, comp = threadIdx.x & 3;
        const float* Cf = (const float*)Cb;       // [32][32][4] flat
        float s = 0.0f;
        #pragma unroll
        for (int w = 0; w < 32; ++w) s += Cf[(w * 32 + g) * 4 + comp];
        C[c * DIM + threadIdx.x] = s;
    }
}

// ---------------------------------------------------------------------------
// KB: 512-thread blocks (2 waves/SIMD). Prefetch z/labels/inv into registers
// BEFORE the S-scan so HBM latency hides under it, then per-row loss.
__global__ void __launch_bounds__(512)
kb_loss(const float* __restrict__ z, const int* __restrict__ labels,
        const float* __restrict__ C, const float* __restrict__ invb,
        float* __restrict__ out)
{
    const int tid  = threadIdx.x;
    const int lane = tid & 63;
    const int sub  = lane & 31;
    const int half = lane >> 5;
    const int wid  = tid >> 6;                       // 0..7
    const int hw   = (blockIdx.x * 8 + wid) * 2 + half;  // 0..4095

    const int rowA = hw, rowB = hw + 4096;

    // ---- issue-early: row data into registers before the S-scan ----
    float4 vA = *(const float4*)(z + (size_t)rowA * DIM + sub * 4);
    float4 vB = *(const float4*)(z + (size_t)rowB * DIM + sub * 4);
    int   lA = labels[rowA], lB = labels[rowB];
    float iA = invb[rowA],   iB = invb[rowB];

    // ---- S-scan: 16 chunks x 32 dim-groups ----
    __shared__ float4 Sp[16][32];
    __shared__ float4 S4s[32];
    {
        int g = tid & 31, chunk = tid >> 5;
        float4 s = make_float4(0.0f, 0.0f, 0.0f, 0.0f);
        for (int cc = chunk; cc < NCLASS; cc += 16) {
            float4 v = *(const float4*)(C + cc * DIM + g * 4);
            s.x += v.x; s.y += v.y; s.z += v.z; s.w += v.w;
        }
        Sp[chunk][g] = s;
    }
    __syncthreads();
    if (tid < 32) {
        float4 s = make_float4(0.0f, 0.0f, 0.0f, 0.0f);
        #pragma unroll
        for (int ch = 0; ch < 16; ++ch) {
            float4 v = Sp[ch][tid];
            s.x += v.x; s.y += v.y; s.z += v.z; s.w += v.w;
        }
        S4s[tid] = s;
    }
    __syncthreads();

    float4 s4 = S4s[sub];
    float4 cA = *(const float4*)(C + (size_t)lA * DIM + sub * 4);
    float4 cB = *(const float4*)(C + (size_t)lB * DIM + sub * 4);

    float dcA = vA.x * cA.x + vA.y * cA.y + vA.z * cA.z + vA.w * cA.w;
    float dtA = vA.x * s4.x + vA.y * s4.y + vA.z * s4.z + vA.w * s4.w;
    float dcB = vB.x * cB.x + vB.y * cB.y + vB.z * cB.z + vB.w * cB.w;
    float dtB = vB.x * s4.x + vB.y * s4.y + vB.z * s4.z + vB.w * s4.w;
    #pragma unroll
    for (int off = 1; off < 32; off <<= 1) {
        dcA += __shfl_xor(dcA, off);
        dtA += __shfl_xor(dtA, off);
        dcB += __shfl_xor(dcB, off);
        dtB += __shfl_xor(dtB, off);
    }
    float lacc = -__logf((dcA * iA - 1.0f) / (dtA * iA))
                 -__logf((dcB * iB - 1.0f) / (dtB * iB));

    lacc += __shfl_xor(lacc, 32);
    __shared__ float wacc[8];
    if (lane == 0) wacc[wid] = lacc;
    __syncthreads();
    if (tid == 0) {
        float b = wacc[0] + wacc[1] + wacc[2] + wacc[3]
                + wacc[4] + wacc[5] + wacc[6] + wacc[7];
        unsafeAtomicAdd(out, b * (1.0f / (float)N_ROWS));
    }
}

extern "C" void kernel_launch(void* const* d_in, const int* in_sizes, int n_in,
                              void* d_out, int out_size, void* d_ws, size_t ws_size,
                              hipStream_t stream) {
    const float* z      = (const float*)d_in[0];
    const int*   labels = (const int*)d_in[1];
    float* out  = (float*)d_out;
    float* ws   = (float*)d_ws;
    float* C    = ws;
    float* invb = ws + INV_OFF;

    (void)in_sizes; (void)n_in; (void)out_size; (void)ws_size;

    ka_class_sums<<<NCLASS, 1024, 0, stream>>>(z, labels, C, invb, out);
    kb_loss      <<<256,    512,  0, stream>>>(z, labels, C, invb, out);
}